// Round 9
// baseline (1379.838 us; speedup 1.0000x reference)
//
#include <hip/hip_runtime.h>
#include <hip/hip_bf16.h>

// Problem constants: B=16, S=256, V=32000, E=256, H=8, L=2, FFN=1024, NC=4, DK=32, NQ=256

typedef __attribute__((ext_vector_type(8))) short bf8v;   // 8 bf16 in 4 VGPRs
typedef __attribute__((ext_vector_type(4))) float f4v;    // MFMA accumulator
#define MFMA16 __builtin_amdgcn_mfma_f32_16x16x32_bf16

__device__ __forceinline__ unsigned short f2bf(float f) {
  unsigned u = __builtin_bit_cast(unsigned, f);
  u += 0x7fffu + ((u >> 16) & 1u);
  return (unsigned short)(u >> 16);
}
__device__ __forceinline__ float rcp_f(float x) { return __builtin_amdgcn_rcpf(x); }
__device__ __forceinline__ float sigm(float x) { return rcp_f(1.f + __expf(-x)); }
__device__ __forceinline__ float tanh_f(float x) { return 1.f - 2.f * rcp_f(__expf(2.f * x) + 1.f); }

// v_dot2_f32_bf16: acc += a.x*b.x + a.y*b.y  (packed bf16 pairs in uint)
#define DOT2BF(acc, a, b) \
  asm("v_dot2_f32_bf16 %0, %1, %2, %0" : "+v"(acc) : "v"(a), "v"(b))

// ---------------- embedding gather -> bf16 ----------------
__global__ void embed_kernel(const int* __restrict__ x, const float* __restrict__ tab,
                             unsigned short* __restrict__ eb) {
  int tok = blockIdx.x, tid = threadIdx.x;
  eb[tok * 256 + tid] = f2bf(tab[x[tok] * 256 + tid]);
}

// ---- transpose to bf16: W [K][N] f32 -> T[n][k] bf16 ; blockIdx.z batches slices ----
__global__ void pack_bt(const float* __restrict__ W, int K, int N,
                        unsigned short* __restrict__ Th, long wz, long tz) {
  __shared__ float tile[64][65];
  W += (long)blockIdx.z * wz;
  Th += (long)blockIdx.z * tz;
  int n0 = blockIdx.x * 64, k0 = blockIdx.y * 64;
  int tid = threadIdx.x, tx = tid & 63, ty = tid >> 6;
  for (int r = ty; r < 64; r += 4) tile[r][tx] = W[(k0 + r) * N + n0 + tx];
  __syncthreads();
  for (int r = ty; r < 64; r += 4) {
    Th[(n0 + r) * K + k0 + tx] = f2bf(tile[tx][r]);  // = W[k0+tx][n0+r]
  }
}

// ---- pack h-part of gate (blockIdx.y) as bf16 d-pairs, uint4-friendly LDS layout ----
__global__ void pack_wl_kernel(const float* __restrict__ lstmW, unsigned* __restrict__ WLg) {
  int gate = blockIdx.y;
  int o = blockIdx.x * 256 + threadIdx.x;  // < 32768
  int c = o & 3;
  int q = (o >> 2) & 255;
  int p4 = o >> 10;  // 0..31
  int d = 2 * (p4 * 4 + c);
  unsigned lo = f2bf(lstmW[(gate * 512 + 256 + d) * 256 + q]);
  unsigned hi = f2bf(lstmW[(gate * 512 + 256 + d + 1) * 256 + q]);
  WLg[gate * 32768 + o] = lo | (hi << 16);
}

// ---------------- MFMA GEMM 128x128: C = A*B + bias ----------------
__global__ void __launch_bounds__(256) gemm_mfma(const unsigned short* __restrict__ A,
                                                 const unsigned short* __restrict__ B,
                                                 const float* __restrict__ bias,
                                                 float* __restrict__ Cf,
                                                 unsigned short* __restrict__ Cb,
                                                 int M, int N, int K, int mode) {
  __shared__ unsigned short As[128 * 40];
  __shared__ unsigned short Bs[128 * 40];

  const int tid = threadIdx.x;
  const int lane = tid & 63;
  const int wid = tid >> 6;
  const int wr = wid >> 1, wc = wid & 1;
  const int bm = blockIdx.y * 128, bn = blockIdx.x * 128;

  const int srow = tid >> 2;
  const int scol = (tid & 3) * 8;

  f4v acc[4][4] = {};

  for (int kt = 0; kt < K; kt += 32) {
#pragma unroll
    for (int p = 0; p < 2; ++p) {
      int r = srow + p * 64;
      *(uint4*)(&As[r * 40 + scol]) = *(const uint4*)(&A[(bm + r) * K + kt + scol]);
      *(uint4*)(&Bs[r * 40 + scol]) = *(const uint4*)(&B[(bn + r) * K + kt + scol]);
    }
    __syncthreads();

    bf8v a[4], b[4];
    const int kq = (lane >> 4) * 8;
#pragma unroll
    for (int f = 0; f < 4; ++f) {
      a[f] = *(const bf8v*)(&As[(wr * 64 + f * 16 + (lane & 15)) * 40 + kq]);
      b[f] = *(const bf8v*)(&Bs[(wc * 64 + f * 16 + (lane & 15)) * 40 + kq]);
    }
#pragma unroll
    for (int fm = 0; fm < 4; ++fm)
#pragma unroll
      for (int fn = 0; fn < 4; ++fn)
        acc[fm][fn] = MFMA16(a[fm], b[fn], acc[fm][fn], 0, 0, 0);
    __syncthreads();
  }

#pragma unroll
  for (int fm = 0; fm < 4; ++fm)
#pragma unroll
    for (int fn = 0; fn < 4; ++fn) {
      int c = bn + wc * 64 + fn * 16 + (lane & 15);
      int r0 = bm + wr * 64 + fm * 16 + ((lane >> 4) << 2);
      float bv = bias[c];
#pragma unroll
      for (int j = 0; j < 4; ++j) {
        float v = acc[fm][fn][j] + bv;
        if (mode == 1) {
          Cb[(r0 + j) * N + c] = f2bf(fmaxf(v, 0.f));
        } else {
          Cf[(r0 + j) * N + c] = v;
        }
      }
    }
}

// ---------------- MFMA GEMM 64x64 tile (for N=256: 4x the blocks of 128-tile) ----------------
__global__ void __launch_bounds__(256) gemm64(const unsigned short* __restrict__ A,
                                              const unsigned short* __restrict__ B,
                                              const float* __restrict__ bias,
                                              float* __restrict__ Cf,
                                              int M, int N, int K) {
  __shared__ unsigned short As[64 * 40];
  __shared__ unsigned short Bs[64 * 40];

  const int tid = threadIdx.x;
  const int lane = tid & 63;
  const int wid = tid >> 6;          // wave owns M-rows [wid*16, wid*16+16)
  const int bm = blockIdx.y * 64, bn = blockIdx.x * 64;
  const int srow = tid >> 2;         // 0..63
  const int scol = (tid & 3) * 8;

  f4v acc[4] = {};

  for (int kt = 0; kt < K; kt += 32) {
    *(uint4*)(&As[srow * 40 + scol]) = *(const uint4*)(&A[(bm + srow) * K + kt + scol]);
    *(uint4*)(&Bs[srow * 40 + scol]) = *(const uint4*)(&B[(bn + srow) * K + kt + scol]);
    __syncthreads();

    const int kq = (lane >> 4) * 8;
    bf8v a = *(const bf8v*)(&As[(wid * 16 + (lane & 15)) * 40 + kq]);
#pragma unroll
    for (int f = 0; f < 4; ++f) {
      bf8v b = *(const bf8v*)(&Bs[(f * 16 + (lane & 15)) * 40 + kq]);
      acc[f] = MFMA16(a, b, acc[f], 0, 0, 0);
    }
    __syncthreads();
  }

#pragma unroll
  for (int f = 0; f < 4; ++f) {
    int c = bn + f * 16 + (lane & 15);
    int r0 = bm + wid * 16 + ((lane >> 4) << 2);
    float bv = bias[c];
#pragma unroll
    for (int j = 0; j < 4; ++j) {
      Cf[(r0 + j) * N + c] = acc[f][j] + bv;
    }
  }
}

// ---------------- QLSTM: 64 blocks = (batch, gate); LDS weights; flag+bulk exchange ----------
// Exchange per step: 256 relaxed agent-atomic value stores (straight to MALL), barrier
// (pre-barrier vmcnt(0) drains every wave's stores), ONE release flag per gate; readers
// poll 3 partner flags with 3 lanes, barrier, then 3 coalesced value loads per thread.
// Combine replicated in all 4 gate blocks (bitwise-identical); g==0 writes h (+PE fused).
__global__ void __launch_bounds__(512)
lstm_kernel(const unsigned* __restrict__ WLgAll,
            const float* __restrict__ lstmTh,
            const float* __restrict__ xw,
            float* __restrict__ hb,
            unsigned* __restrict__ qv32,
            unsigned* __restrict__ flg) {
  extern __shared__ char smem[];
  unsigned* WL = (unsigned*)smem;               // [32][256] uint4 rows (131072 B)
  float* part = (float*)(smem + 131072);        // [2][256]
  float* wtot = part + 512;                     // [4] (+4 pad)
  unsigned* hp = (unsigned*)(wtot + 8);         // [128] packed bf16 h pairs (16B aligned)

  const int t = threadIdx.x;
  const int b = blockIdx.x >> 2;
  const int g = blockIdx.x & 3;
  const int q = t & 255;
  const int s = t >> 8;
  const int lane = t & 63;
  const int w = t >> 6;

  {
    const uint4* src = (const uint4*)WLgAll + g * 8192;
    uint4* dst = (uint4*)WL;
    for (int j = t; j < 8192; j += 512) dst[j] = src[j];
  }
  const float th = lstmTh[g * 256 + q];
  float cx = 0.f;  // replicated per (b,q); valid for t<256
  if (t < 128) hp[t] = 0u;
  __syncthreads();

  const uint4* WL4 = (const uint4*)WL;
  const uint4* hp4 = (const uint4*)hp;
  const int xrow = (b << 8) * 1024 + g * 256 + q;

  for (int st = 0; st < 256; ++st) {
    float xv = xw[xrow + st * 1024];
    const int par = st & 1;
    const int fbase = (par * 16 + b) * 4;
    const unsigned tag = (unsigned)(st + 1);

    // ---- GEMV half-dot for own gate: 128 d = 64 pairs = 16 uint4 (all LDS) ----
    float acc = 0.f;
#pragma unroll
    for (int i4 = 0; i4 < 16; ++i4) {
      uint4 hh = hp4[(s << 4) + i4];              // wave-uniform -> broadcast
      uint4 wv = WL4[((s << 4) + i4) * 256 + q];  // consecutive b128
      DOT2BF(acc, wv.x, hh.x); DOT2BF(acc, wv.y, hh.y);
      DOT2BF(acc, wv.z, hh.z); DOT2BF(acc, wv.w, hh.w);
    }
    part[s * 256 + q] = acc;
    __syncthreads();  // bar1: partials ready

    float v = 0.f;
    if (t < 256) {
      float z = part[q] + part[256 + q] + xv + th;
      v = __cosf(z);
#pragma unroll
      for (int off = 1; off < 64; off <<= 1) {
        float o = __shfl_up(v, off, 64);
        if (lane >= off) v *= o;
      }
      if (lane == 63) wtot[w] = v;
    }
    __syncthreads();  // bar2: wtot ready

    if (t < 256) {
      float p = 1.f;
      int j = q >> 6;
      for (int k = 0; k < j; ++k) p *= wtot[k];
      v *= p;
      // publish own gate value straight to MALL (relaxed agent atomic)
      __hip_atomic_store(&qv32[(fbase + g) * 256 + q],
                         __builtin_bit_cast(unsigned, v),
                         __ATOMIC_RELAXED, __HIP_MEMORY_SCOPE_AGENT);
    }
    __syncthreads();  // bar3: every wave drained its stores (vmcnt(0) before s_barrier)

    if (t >= 256 && t < 320) {  // wave 4: flag publish + partner polling
      if (t == 256) {
        __hip_atomic_store(&flg[fbase + g], tag, __ATOMIC_RELEASE,
                           __HIP_MEMORY_SCOPE_AGENT);
      }
      int l = t - 256;
      if (l < 3) {
        int pg = (g + 1 + l) & 3;
        while (__hip_atomic_load(&flg[fbase + pg], __ATOMIC_RELAXED,
                                 __HIP_MEMORY_SCOPE_AGENT) < tag) {
        }
      }
    }
    __syncthreads();  // bar4: partner values available

    if (t < 256) {
      float gv[4];
#pragma unroll
      for (int gg = 0; gg < 4; ++gg) {
        if (gg == g) {
          gv[gg] = v;
        } else {
          unsigned u = __hip_atomic_load(&qv32[(fbase + gg) * 256 + q],
                                         __ATOMIC_RELAXED, __HIP_MEMORY_SCOPE_AGENT);
          gv[gg] = __builtin_bit_cast(float, u);
        }
      }
      float fg = sigm(gv[0]);
      float ig = sigm(gv[1]);
      float gg_ = tanh_f(gv[2]);
      float og = sigm(gv[3]);
      cx = fg * cx + ig * gg_;
      float hv = og * tanh_f(cx);
      if (g == 0) {
        // fused sinusoidal PE on the h written for downstream (recurrence uses raw hv)
        float ang = (float)st * __expf((float)(q >> 1) * -0.07195578415622253f);
        float pe = (q & 1) ? __cosf(ang) : __sinf(ang);
        hb[((b << 8) + st) * 256 + q] = hv + pe;
      }
      float nb = __shfl_xor(hv, 1, 64);
      if ((t & 1) == 0) hp[t >> 1] = (unsigned)f2bf(hv) | ((unsigned)f2bf(nb) << 16);
    }
    __syncthreads();  // bar5: hp ready for next step
  }
}

// ---------------- qproj x3 fused (f32 out, contiguous q/k/v buffers) ----------------
__global__ void qproj3_kernel(const float* __restrict__ hin, const float* __restrict__ thetas,
                              float* __restrict__ outbase) {
  __shared__ float wtot[4];
  int tok = blockIdx.x, y = blockIdx.y;
  int tid = threadIdx.x, lane = tid & 63, wid = tid >> 6;
  const float* theta = thetas + y * 256;
  float* out = outbase + (long)y * 1048576;
  float v = __cosf(hin[tok * 256 + tid] + theta[tid]);
#pragma unroll
  for (int off = 1; off < 64; off <<= 1) {
    float o = __shfl_up(v, off, 64);
    if (lane >= off) v *= o;
  }
  if (lane == 63) wtot[wid] = v;
  __syncthreads();
  float pre = 1.f;
  for (int w = 0; w < wid; ++w) pre *= wtot[w];
  out[tok * 256 + tid] = v * pre;
}

// ---------------- fused layernorm(h+delta)->h  +  qproj->bf16 (FFN input) ----------------
__global__ void ln_qproj_kernel(float* __restrict__ hio, const float* __restrict__ delta,
                                const float* __restrict__ gamma, const float* __restrict__ beta,
                                const float* __restrict__ theta,
                                unsigned short* __restrict__ outb) {
  __shared__ float red[16];
  __shared__ float wtot[4];
  int tok = blockIdx.x, tid = threadIdx.x, lane = tid & 63, wid = tid >> 6;
  float v = hio[tok * 256 + tid] + delta[tok * 256 + tid];
  float s1 = v, s2 = v * v;
#pragma unroll
  for (int off = 32; off; off >>= 1) {
    s1 += __shfl_xor(s1, off, 64);
    s2 += __shfl_xor(s2, off, 64);
  }
  if (lane == 0) { red[wid] = s1; red[wid + 8] = s2; }
  __syncthreads();
  float t1 = red[0] + red[1] + red[2] + red[3];
  float t2 = red[8] + red[9] + red[10] + red[11];
  float mean = t1 * (1.f / 256.f);
  float var = t2 * (1.f / 256.f) - mean * mean;
  float w = rsqrtf(var + 1e-5f);
  float val = (v - mean) * w * gamma[tid] + beta[tid];
  hio[tok * 256 + tid] = val;
  float c = __cosf(val + theta[tid]);
#pragma unroll
  for (int off = 1; off < 64; off <<= 1) {
    float o = __shfl_up(c, off, 64);
    if (lane >= off) c *= o;
  }
  if (lane == 63) wtot[wid] = c;
  __syncthreads();
  float pre = 1.f;
  for (int k = 0; k < wid; ++k) pre *= wtot[k];
  outb[tok * 256 + tid] = f2bf(c * pre);
}

// ---------------- attention: block per (head,batch); vectorized LDS ----------------
__global__ void __launch_bounds__(256, 1) attn_kernel(const float* __restrict__ qb,
                                                      const float* __restrict__ kb,
                                                      const float* __restrict__ vb,
                                                      unsigned short* __restrict__ outb) {
  extern __shared__ float sm[];
  float* Qs = sm;                 // [256][36]
  float* Ks = Qs + 256 * 36;      // [256][36]
  float* Vs = Ks + 256 * 36;      // [32][260]  d-major
  float* ps = Vs + 32 * 260;      // [4][256]
  int hd = blockIdx.x, b = blockIdx.y;
  int tid = threadIdx.x, lane = tid & 63, wid = tid >> 6;
  const float scale = 0.17677669529663687f;  // 1/sqrt(32)

  for (int i = tid; i < 256 * 32; i += 256) {
    int r = i >> 5, d = i & 31;
    int src = (b * 256 + r) * 256 + hd * 32 + d;
    Qs[r * 36 + d] = qb[src];
    Ks[r * 36 + d] = kb[src];
    Vs[d * 260 + r] = vb[src];
  }
  __syncthreads();

  float* pw = ps + wid * 256;
  for (int r = wid; r < 256; r += 4) {
    float4 qreg[8];
    const float4* qrow = (const float4*)(Qs + r * 36);
#pragma unroll
    for (int i = 0; i < 8; ++i) qreg[i] = qrow[i];
    float s[4];
#pragma unroll
    for (int j = 0; j < 4; ++j) {
      int k = lane + 64 * j;
      const float4* kr = (const float4*)(Ks + k * 36);
      float a = 0.f;
#pragma unroll
      for (int i = 0; i < 8; ++i) {
        float4 kv = kr[i];
        a += qreg[i].x * kv.x + qreg[i].y * kv.y + qreg[i].z * kv.z + qreg[i].w * kv.w;
      }
      s[j] = a * scale;
    }
    float m = fmaxf(fmaxf(s[0], s[1]), fmaxf(s[2], s[3]));
#pragma unroll
    for (int off = 32; off; off >>= 1) m = fmaxf(m, __shfl_xor(m, off, 64));
    float p[4], sum = 0.f;
#pragma unroll
    for (int j = 0; j < 4; ++j) { p[j] = __expf(s[j] - m); sum += p[j]; }
#pragma unroll
    for (int off = 32; off; off >>= 1) sum += __shfl_xor(sum, off, 64);
    float inv = rcp_f(sum);
#pragma unroll
    for (int j = 0; j < 4; ++j) pw[lane + 64 * j] = p[j] * inv;
    int d = lane & 31, half = lane >> 5;
    const float4* pv = (const float4*)(pw + half * 128);
    const float4* v4 = (const float4*)(Vs + d * 260 + half * 128);
    float a = 0.f;
#pragma unroll
    for (int i = 0; i < 32; ++i) {
      float4 pp = pv[i];
      float4 vv = v4[i];
      a += pp.x * vv.x + pp.y * vv.y + pp.z * vv.z + pp.w * vv.w;
    }
    a += __shfl_down(a, 32, 64);
    if (lane < 32) outb[(b * 256 + r) * 256 + hd * 32 + d] = f2bf(a);
  }
}

// ---------------- layernorm(h + delta) -> h ----------------
__global__ void ln_kernel(float* __restrict__ hio, const float* __restrict__ delta,
                          const float* __restrict__ gamma, const float* __restrict__ beta) {
  __shared__ float red[16];
  int tok = blockIdx.x, tid = threadIdx.x, lane = tid & 63, wid = tid >> 6;
  float v = hio[tok * 256 + tid] + delta[tok * 256 + tid];
  float s1 = v, s2 = v * v;
#pragma unroll
  for (int off = 32; off; off >>= 1) {
    s1 += __shfl_xor(s1, off, 64);
    s2 += __shfl_xor(s2, off, 64);
  }
  if (lane == 0) { red[wid] = s1; red[wid + 8] = s2; }
  __syncthreads();
  float t1 = red[0] + red[1] + red[2] + red[3];
  float t2 = red[8] + red[9] + red[10] + red[11];
  float mean = t1 * (1.f / 256.f);
  float var = t2 * (1.f / 256.f) - mean * mean;
  float w = rsqrtf(var + 1e-5f);
  hio[tok * 256 + tid] = (v - mean) * w * gamma[tid] + beta[tid];
}

// ---------------- pool stage A: partial sums over 16-step chunks ----------------
__global__ void poolA_kernel(const float* __restrict__ h, float* __restrict__ partial) {
  int bx = blockIdx.x;  // 0..255
  int b = bx >> 4, ch = bx & 15;
  int tid = threadIdx.x;
  float s = 0.f;
  for (int tt = ch * 16; tt < ch * 16 + 16; ++tt) s += h[((b << 8) + tt) * 256 + tid];
  partial[bx * 256 + tid] = s;
}

// ---------------- pool stage B: reduce + classifier ----------------
__global__ void poolB_kernel(const float* __restrict__ partial, const float* __restrict__ clsW,
                             const float* __restrict__ clsb, float* __restrict__ out) {
  __shared__ float pl[256];
  __shared__ float red[8];
  int b = blockIdx.x, tid = threadIdx.x, lane = tid & 63, wid = tid >> 6;
  float s = 0.f;
  for (int ch = 0; ch < 16; ++ch) s += partial[(b * 16 + ch) * 256 + tid];
  pl[tid] = s * (1.f / 256.f);
  __syncthreads();
  for (int c = 0; c < 4; ++c) {
    float v = pl[tid] * clsW[tid * 4 + c];
#pragma unroll
    for (int off = 32; off; off >>= 1) v += __shfl_xor(v, off, 64);
    if (lane == 0) red[wid] = v;
    __syncthreads();
    if (tid == 0) out[b * 4 + c] = red[0] + red[1] + red[2] + red[3] + clsb[c];
    __syncthreads();
  }
}

extern "C" void kernel_launch(void* const* d_in, const int* in_sizes, int n_in,
                              void* d_out, int out_size, void* d_ws, size_t ws_size,
                              hipStream_t stream) {
  const int* x = (const int*)d_in[0];
  const float* token_emb = (const float*)d_in[1];
  const float* lstm_W = (const float*)d_in[2];
  const float* lstm_b = (const float*)d_in[3];
  const float* lstm_th = (const float*)d_in[4];
  const float* ln1_g = (const float*)d_in[5];
  const float* ln1_b = (const float*)d_in[6];
  const float* ln2_g = (const float*)d_in[7];
  const float* ln2_b = (const float*)d_in[8];
  const float* qkv_th = (const float*)d_in[9];
  const float* comb_W = (const float*)d_in[10];
  const float* comb_b = (const float*)d_in[11];
  const float* ffn_th = (const float*)d_in[12];
  const float* lin1_W = (const float*)d_in[13];
  const float* lin1_b = (const float*)d_in[14];
  const float* lin2_W = (const float*)d_in[15];
  const float* lin2_b = (const float*)d_in[16];
  const float* cls_W = (const float*)d_in[17];
  const float* cls_b = (const float*)d_in[18];

  float* ws = (float*)d_ws;
  typedef unsigned short ushort_t;
  ushort_t* emb_b = (ushort_t*)ws;       // 1M f32 region: emb bf16 pre-loop / attn bf16 in-loop
  ushort_t* att_b = emb_b;
  float* xw = ws + 1048576;              // 4M f32: xw pre-loop / ffh bf16 in-loop
  ushort_t* ffh_b = (ushort_t*)xw;
  float* hb = ws + 5242880;   // 1M
  float* qq = ws + 6291456;   // 1M  (qq,kk,vv contiguous for fused qproj3)
  float* kk = ws + 7340032;   // 1M
  float* vv = ws + 8388608;   // 1M
  float* tmp = ws + 9437184;  // 1M; first 131072 u32 reused pre-loop for lstm weight pack
  unsigned* WLg = (unsigned*)tmp;                // 4 x 32768 uints (all gates)
  ushort_t* ffq_b = (ushort_t*)(ws + 10485760);  // 1M ushort
  ushort_t* wxt_b = (ushort_t*)(ws + 11534336);  // 262144 (4 gates x [256][256])
  ushort_t* cmb_b = wxt_b + 262144;              // 2 x 65536
  ushort_t* l1_b = cmb_b + 131072;               // 2 x 262144
  ushort_t* l2_b = l1_b + 524288;                // 2 x 262144  (ends at f32 idx 12255232)
  unsigned* qv32 = (unsigned*)(ws + 12255232);   // 2*16*4*256 u32 = 128 KB
  unsigned* flg = (unsigned*)(ws + 12287999 + 1);  // 128 u32 (at 12288000)
  float* partial = ws + 12288128;                // 256*256 f32 = 256 KB

  const int LSTM_LDS = 131072 + 2048 + 32 + 512;                   // 133664 B
  const int ATT_LDS = (256 * 36 * 2 + 32 * 260 + 4 * 256) * 4;     // 111104 B
  (void)hipFuncSetAttribute(reinterpret_cast<const void*>(lstm_kernel),
                            hipFuncAttributeMaxDynamicSharedMemorySize, LSTM_LDS);
  (void)hipFuncSetAttribute(reinterpret_cast<const void*>(attn_kernel),
                            hipFuncAttributeMaxDynamicSharedMemorySize, ATT_LDS);

  // flags must start below 1 every launch (values are gated by flags; no memset needed)
  hipMemsetAsync(flg, 0, 128 * 4, stream);

  embed_kernel<<<4096, 256, 0, stream>>>(x, token_emb, emb_b);
  pack_wl_kernel<<<dim3(128, 4), 256, 0, stream>>>(lstm_W, WLg);
  pack_bt<<<dim3(4, 4, 4), 256, 0, stream>>>(lstm_W, 256, 256, wxt_b, 131072, 65536);
  pack_bt<<<dim3(4, 4, 2), 256, 0, stream>>>(comb_W, 256, 256, cmb_b, 65536, 65536);
  pack_bt<<<dim3(16, 4, 2), 256, 0, stream>>>(lin1_W, 256, 1024, l1_b, 262144, 262144);
  pack_bt<<<dim3(4, 16, 2), 256, 0, stream>>>(lin2_W, 1024, 256, l2_b, 262144, 262144);

  // xw = emb @ Wx + lstm_b : M=4096 N=1024 K=256
  gemm_mfma<<<dim3(8, 32), 256, 0, stream>>>(emb_b, wxt_b, lstm_b,
                                             xw, nullptr, 4096, 1024, 256, 0);
  lstm_kernel<<<64, 512, LSTM_LDS, stream>>>(WLg, lstm_th, xw, hb, qv32, flg);

  for (int l = 0; l < 2; ++l) {
    qproj3_kernel<<<dim3(4096, 3), 256, 0, stream>>>(hb, qkv_th + l * 768, qq);
    attn_kernel<<<dim3(8, 16), 256, ATT_LDS, stream>>>(qq, kk, vv, att_b);
    gemm64<<<dim3(4, 64), 256, 0, stream>>>(att_b, cmb_b + l * 65536, comb_b + l * 256,
                                            tmp, 4096, 256, 256);
    ln_qproj_kernel<<<4096, 256, 0, stream>>>(hb, tmp, ln1_g + l * 256, ln1_b + l * 256,
                                              ffn_th + l * 256, ffq_b);
    gemm_mfma<<<dim3(8, 32), 256, 0, stream>>>(ffq_b, l1_b + l * 262144, lin1_b + l * 1024,
                                               nullptr, ffh_b, 4096, 1024, 256, 1);
    gemm64<<<dim3(4, 64), 256, 0, stream>>>(ffh_b, l2_b + l * 262144, lin2_b + l * 256,
                                            tmp, 4096, 256, 1024);
    ln_kernel<<<4096, 256, 0, stream>>>(hb, tmp, ln2_g + l * 256, ln2_b + l * 256);
  }

  poolA_kernel<<<256, 256, 0, stream>>>(hb, partial);
  poolB_kernel<<<16, 256, 0, stream>>>(partial, cls_W, cls_b, (float*)d_out);
}